// Round 7
// baseline (1428.857 us; speedup 1.0000x reference)
//
#include <hip/hip_runtime.h>

typedef _Float16 half8_t __attribute__((ext_vector_type(8)));
typedef float    f32x4   __attribute__((ext_vector_type(4)));

#define T_STEPS 1024
#define BATCH   128
#define HID     128
#define GATES   512
#define STACK   1024

__device__ __forceinline__ float sigf(float x)     { return 1.0f / (1.0f + __expf(-x)); }
__device__ __forceinline__ float tanhfast(float x) { return 1.0f - 2.0f / (1.0f + __expf(2.0f * x)); }
__device__ __forceinline__ float sel4(f32x4 v, int s) {
    float r = v[0];
    r = (s == 1) ? v[1] : r;
    r = (s == 2) ? v[2] : r;
    r = (s == 3) ? v[3] : r;
    return r;
}

// grid = 256: blocks [0,128) = layer 0 of row r, [128,256) = layer 1 of row r.
// Wave w owns units [16w,16w+16): gate tile g has A-rows {128g+16w+m}, so
// lane (ml,kg) ends up with all 4 gates of units 16w+4kg+reg in-register ->
// epilogue needs NO LDS round trip and NO second barrier. Global stores are
// deferred one step so the single barrier's vmcnt(0) drain overlaps MFMA.
__launch_bounds__(512, 2)
__global__ void stack_lstm_pipe(const float* __restrict__ inputs,
                                const int*   __restrict__ ops,
                                const float* __restrict__ w_ih,
                                const float* __restrict__ w_hh,
                                const float* __restrict__ b_ih,
                                const float* __restrict__ b_hh,
                                float* __restrict__ out,
                                unsigned int* __restrict__ ring,  // [D][BATCH][HID]
                                int* __restrict__ cons,           // [BATCH] watermark
                                int D)                            // ring depth, pow2
{
    const int bx    = blockIdx.x;
    const int layer = bx >> 7;      // 0 or 1
    const int r     = bx & 127;     // batch row
    const int tid   = threadIdx.x;  // 0..511
    const int w8    = tid >> 6;     // wave -> units [16w8, 16w8+16)
    const int ln    = tid & 63;
    const int ml    = ln & 15;
    const int kg    = ln >> 4;      // k-group 0..3
    const int usel  = ml & 3;
    const int unit  = 16 * w8 + 4 * kg + usel;  // unit this lane's epilogue owns
    const bool writer = (ml < 4);               // unique lane per unit
    const int mask  = D - 1;

    __shared__ __align__(16) _Float16 vin[2][256];  // [x(128) | h_top(128)]
    __shared__ int ops_s[T_STEPS];

    // ---- weights as MFMA A-fragments: tile g covers rows {128g + 16w8 + m}.
    // A[m=ml][k = 32kc + 8kg + j]; virtual K: k<128 -> w_ih, else w_hh.
    half8_t wfrag[32];  // [g*8 + kc]
#pragma unroll
    for (int g = 0; g < 4; ++g) {
        const int R = layer * GATES + 128 * g + 16 * w8 + ml;
        const float* rowi = w_ih + (size_t)R * HID;
        const float* rowh = w_hh + (size_t)R * HID;
#pragma unroll
        for (int kc = 0; kc < 8; ++kc) {
            const int k0 = 32 * kc + 8 * kg;
            const float* src = (k0 < 128) ? (rowi + k0) : (rowh + (k0 - 128));
            half8_t h;
#pragma unroll
            for (int j = 0; j < 8; j += 2) {
                float2 f = *reinterpret_cast<const float2*>(src + j);
                h[j]     = (_Float16)f.x;
                h[j + 1] = (_Float16)f.y;
            }
            wfrag[g * 8 + kc] = h;
        }
    }
    // biases as C-init vectors: biasv[g][reg] = bias of gate g, unit 16w8+4kg+reg
    f32x4 biasv[4];
#pragma unroll
    for (int g = 0; g < 4; ++g)
#pragma unroll
        for (int reg = 0; reg < 4; ++reg) {
            const int uu = 16 * w8 + 4 * kg + reg;
            biasv[g][reg] = b_ih[layer * GATES + 128 * g + uu]
                          + b_hh[layer * GATES + 128 * g + uu];
        }

    ops_s[tid]       = ops[(size_t)tid * BATCH + r];
    ops_s[tid + 512] = ops[(size_t)(tid + 512) * BATCH + r];

    float c_cur = 0.f, h_top = 0.f;
    int   pos = 0, cons_seen = 0;
    float xs = 0.f;            // L0 stagers: x(t+1) pipeline register
    unsigned int sv_word = 0;  // deferred ring word (L0)
    size_t sv_idx = 0;         // deferred ring index (L0)
    float  sv_val = 0.f;       // deferred out value (L1)
    size_t sv_off = 0;         // deferred out offset (L1)

    // ---- initial staging: vin[0] = [x(0) or h0(0) | zeros]
    if (tid < 128) {
        if (layer == 0) {
            vin[0][tid] = (_Float16)inputs[(size_t)r * HID + tid];
            xs = inputs[(size_t)BATCH * HID + (size_t)r * HID + tid];  // x(1)
        } else {
            unsigned int v;
            do {
                v = __hip_atomic_load(ring + (size_t)r * HID + tid,
                                      __ATOMIC_RELAXED, __HIP_MEMORY_SCOPE_AGENT);
                if ((v & 0xFFFFu) == 1u) break;
                __builtin_amdgcn_s_sleep(1);
            } while (true);
            vin[0][tid] = __builtin_bit_cast(_Float16, (unsigned short)(v >> 16));
        }
        vin[0][HID + tid] = (_Float16)0.f;
    }
    __syncthreads();

    for (int t = 0; t < T_STEPS; ++t) {
        const int buf = t & 1, nb = buf ^ 1;

        // ---- (a) deferred global stores from step t-1 (drain during MFMA)
        if (t > 0 && writer) {
            if (layer == 0) {
                if (D < T_STEPS && t - 1 >= D) {  // ring backpressure (rare)
                    const int need = t - 1 - D;
                    while (cons_seen < need) {
                        cons_seen = __hip_atomic_load(cons + r, __ATOMIC_RELAXED,
                                                      __HIP_MEMORY_SCOPE_AGENT);
                        if (cons_seen >= need) break;
                        __builtin_amdgcn_s_sleep(1);
                    }
                }
                __hip_atomic_store(ring + sv_idx, sv_word,
                                   __ATOMIC_RELAXED, __HIP_MEMORY_SCOPE_AGENT);
            } else {
                out[sv_off] = sv_val;
            }
        }

        // ---- (b) speculative ring load for next step's staging (L1)
        unsigned int spec = 0;
        if (layer == 1 && tid < 128 && t + 1 < T_STEPS)
            spec = __hip_atomic_load(ring + (size_t)((t + 1) & mask) * BATCH * HID
                                          + (size_t)r * HID + tid,
                                     __ATOMIC_RELAXED, __HIP_MEMORY_SCOPE_AGENT);

        // ---- (c) matvec on the MFMA pipe (broadcast-B; acc init = bias)
        f32x4 a0 = biasv[0], a1 = biasv[1], a2 = biasv[2], a3 = biasv[3];
#pragma unroll
        for (int kc = 0; kc < 8; ++kc) {
            const half8_t bfrag =
                *reinterpret_cast<const half8_t*>(&vin[buf][32 * kc + 8 * kg]);
            a0 = __builtin_amdgcn_mfma_f32_16x16x32_f16(wfrag[kc],      bfrag, a0, 0, 0, 0);
            a1 = __builtin_amdgcn_mfma_f32_16x16x32_f16(wfrag[8 + kc],  bfrag, a1, 0, 0, 0);
            a2 = __builtin_amdgcn_mfma_f32_16x16x32_f16(wfrag[16 + kc], bfrag, a2, 0, 0, 0);
            a3 = __builtin_amdgcn_mfma_f32_16x16x32_f16(wfrag[24 + kc], bfrag, a3, 0, 0, 0);
        }

        // ---- (d) in-register epilogue (lane owns all 4 gates of `unit`)
        const int   op = ops_s[t];
        const float gi = sel4(a0, usel);
        const float gf = sel4(a1, usel);
        const float gg = sel4(a2, usel);
        const float go = sel4(a3, usel);
        const float c_new = sigf(gf) * c_cur + sigf(gi) * tanhfast(gg);
        const float h_new = sigf(go) * tanhfast(c_new);

        if (writer) {
            vin[nb][HID + unit] = (_Float16)(op ? h_new : h_top);
            if (layer == 0) {
                const unsigned short hs = __builtin_bit_cast(unsigned short, (_Float16)h_new);
                sv_word = ((unsigned int)hs << 16) | (unsigned int)((t + 1) & 0xFFFF);
                sv_idx  = (size_t)(t & mask) * BATCH * HID + (size_t)r * HID + unit;
            } else {
                sv_val = h_new;
                sv_off = (size_t)(pos + 1) * BATCH * HID + (size_t)r * HID + unit;
            }
        }
        h_top = op ? h_new : h_top;
        c_cur = op ? c_new : c_cur;
        pos += op;

        // ---- (e) stage next step's x-part (lanes 0..127)
        if (tid < 128 && t + 1 < T_STEPS) {
            if (layer == 0) {
                vin[nb][tid] = (_Float16)xs;
                if (t + 2 < T_STEPS)
                    xs = inputs[(size_t)(t + 2) * BATCH * HID + (size_t)r * HID + tid];
            } else {
                unsigned int v = spec;
                const unsigned int expect = (unsigned int)((t + 2) & 0xFFFF);
                while ((v & 0xFFFFu) != expect) {
                    __builtin_amdgcn_s_sleep(1);
                    v = __hip_atomic_load(ring + (size_t)((t + 1) & mask) * BATCH * HID
                                               + (size_t)r * HID + tid,
                                          __ATOMIC_RELAXED, __HIP_MEMORY_SCOPE_AGENT);
                }
                vin[nb][tid] = __builtin_bit_cast(_Float16, (unsigned short)(v >> 16));
            }
        }
        // consumer progress watermark (backpressure input; relaxed, lag-safe)
        if (layer == 1 && tid == 384 && (t & 15) == 0)
            __hip_atomic_store(cons + r, t - 1, __ATOMIC_RELAXED, __HIP_MEMORY_SCOPE_AGENT);

        __syncthreads();  // the ONE barrier per step
    }

    // flush last deferred store
    if (writer) {
        if (layer == 0)
            __hip_atomic_store(ring + sv_idx, sv_word,
                               __ATOMIC_RELAXED, __HIP_MEMORY_SCOPE_AGENT);
        else
            out[sv_off] = sv_val;
    }
    // final pos (float32 — exact for ints <= 1024)
    if (layer == 1 && tid == 0)
        out[(size_t)(STACK + 1) * BATCH * HID + r] = (float)pos;
}

extern "C" void kernel_launch(void* const* d_in, const int* in_sizes, int n_in,
                              void* d_out, int out_size, void* d_ws, size_t ws_size,
                              hipStream_t stream)
{
    (void)in_sizes; (void)n_in;
    const float* inputs = (const float*)d_in[0];
    const int*   ops    = (const int*)d_in[1];
    const float* w_ih   = (const float*)d_in[2];
    const float* w_hh   = (const float*)d_in[3];
    const float* b_ih   = (const float*)d_in[4];
    const float* b_hh   = (const float*)d_in[5];
    float* out = (float*)d_out;

    // ws layout: [0,4096) cons watermark, then tagged u32 ring [D][128][128]
    int* cons = (int*)d_ws;
    unsigned int* ring = (unsigned int*)((char*)d_ws + 4096);

    size_t slot_bytes = (size_t)BATCH * HID * sizeof(unsigned int);
    size_t avail = (ws_size > 4096) ? (ws_size - 4096) / slot_bytes : 1;
    int D = 1;
    while ((size_t)(D * 2) <= avail && D < T_STEPS) D *= 2;

    hipMemsetAsync(d_ws, 0, 4096, stream);  // zero watermarks
    // ring starts 0xAA-poisoned: tag 0xAAAA never matches (expect <= 1025)
    // slots never reached by pos+1 must be zero
    hipMemsetAsync(d_out, 0, (size_t)out_size * sizeof(float), stream);

    stack_lstm_pipe<<<dim3(256), dim3(512), 0, stream>>>(
        inputs, ops, w_ih, w_hh, b_ih, b_hh, out, ring, cons, D);
}